// Round 1
// baseline (2213.146 us; speedup 1.0000x reference)
//
#include <hip/hip_runtime.h>
#include <hip/hip_bf16.h>
#include <math.h>

#define NNODES 50000
#define NEDGES 640000
#define NGRAPH 256
#define CIN 32
#define HD 128
#define NLAYER 5
#define LHID 64
#define COUT 10
#define EPS_GEN 1e-7f

// ---------------- CSR build ----------------
__global__ void hist_kernel(const int* __restrict__ dst, int* __restrict__ deg, int e) {
    int i = blockIdx.x * blockDim.x + threadIdx.x;
    if (i < e) atomicAdd(&deg[dst[i]], 1);
}

__global__ void scan_kernel(const int* __restrict__ deg, int* __restrict__ off,
                            int* __restrict__ cursor, int n) {
    __shared__ int tsum[1024];
    int t = threadIdx.x;
    int chunk = (n + 1023) / 1024;
    int beg = t * chunk;
    int end = min(beg + chunk, n);
    int s = 0;
    for (int i = beg; i < end; ++i) s += deg[i];
    tsum[t] = s;
    __syncthreads();
    for (int d = 1; d < 1024; d <<= 1) {
        int v = (t >= d) ? tsum[t - d] : 0;
        __syncthreads();
        tsum[t] += v;
        __syncthreads();
    }
    int run = (t == 0) ? 0 : tsum[t - 1];
    for (int i = beg; i < end; ++i) {
        off[i] = run; cursor[i] = run;
        run += deg[i];
    }
    if (t == 1023) off[n] = tsum[1023];
}

__global__ void scatter_kernel(const int* __restrict__ src, const int* __restrict__ dst,
                               const int* __restrict__ eattr, int* __restrict__ cursor,
                               int* __restrict__ psrc, int* __restrict__ pattr, int e) {
    int i = blockIdx.x * blockDim.x + threadIdx.x;
    if (i < e) {
        int d = dst[i];
        int slot = atomicAdd(&cursor[d], 1);
        psrc[slot] = src[i];
        pattr[slot] = eattr[i];
    }
}

// ---------------- input FC: h = concat(x, ncc) @ fc_w.T + fc_b ----------------
__global__ void fc_kernel(const float* __restrict__ x, const float* __restrict__ ncc,
                          const float* __restrict__ w, const float* __restrict__ b,
                          float* __restrict__ h, int n) {
    int idx = blockIdx.x * blockDim.x + threadIdx.x;
    if (idx >= n * HD) return;
    int node = idx >> 7;
    int c = idx & 127;
    const float* wr = w + c * 40;
    const float* xr = x + node * CIN;
    const float* nr = ncc + node * 8;
    float acc = b[c];
#pragma unroll
    for (int k = 0; k < CIN; ++k) acc += xr[k] * wr[k];
#pragma unroll
    for (int k = 0; k < 8; ++k) acc += nr[k] * wr[CIN + k];
    h[idx] = acc;
}

// ---------------- softmax aggregation (online) ----------------
// block = 256 threads = 2 nodes x 128 channels
__global__ void agg_kernel(const float* __restrict__ h, const int* __restrict__ off,
                           const int* __restrict__ psrc, const int* __restrict__ pattr,
                           const float* __restrict__ edge_emb, float* __restrict__ x0, int n) {
    int node = blockIdx.x * 2 + (threadIdx.x >> 7);
    int c = threadIdx.x & 127;
    if (node >= n) return;
    int b = off[node], e = off[node + 1];
    float M = -INFINITY, S = 0.f, T = 0.f;
    for (int j = b; j < e; ++j) {
        int s = psrc[j];
        int a = pattr[j];
        float msg = h[s * HD + c] + edge_emb[a * HD + c];
        msg = fmaxf(msg, 0.f) + EPS_GEN;
        if (msg > M) {
            float r = expf(M - msg);   // exp(-inf)=0 handles first iter
            S = S * r + 1.f;
            T = T * r + msg;
            M = msg;
        } else {
            float ev = expf(msg - M);
            S += ev;
            T += ev * msg;
        }
    }
    float agg = (e > b) ? (T / S) : 0.f;
    x0[node * HD + c] = agg + h[node * HD + c];
}

// ---------------- tiled fp32 GEMM: C[M,Nc] = op(A)[M,K] @ W[Nc,K]^T + bias ----------------
// TRANS: A element -> relu(a*scale[k]+shift[k])  (fused BN+ReLU on A)
template <bool TRANS>
__global__ __launch_bounds__(256) void gemm_kernel(
    const float* __restrict__ A, const float* __restrict__ W,
    const float* __restrict__ bias,
    const float* __restrict__ scale, const float* __restrict__ shift,
    float* __restrict__ C, int M, int Nc, int K) {
    __shared__ float As[16][68];
    __shared__ float Ws[16][68];
    int tid = threadIdx.x;
    int m0 = blockIdx.x * 64;
    int j0 = blockIdx.y * 64;
    int lr = tid >> 2;          // 0..63 row of tile being loaded
    int lk = (tid & 3) * 4;     // k sub-offset
    int r  = tid >> 4;          // 0..15 compute row group
    int cg = tid & 15;          // 0..15 compute col group
    float acc[4][4] = {{0.f}};
    for (int k0 = 0; k0 < K; k0 += 16) {
        int am = m0 + lr;
        float4 av = make_float4(0.f, 0.f, 0.f, 0.f);
        if (am < M) av = *reinterpret_cast<const float4*>(&A[(size_t)am * K + k0 + lk]);
        if (TRANS) {
            av.x = fmaxf(av.x * scale[k0 + lk + 0] + shift[k0 + lk + 0], 0.f);
            av.y = fmaxf(av.y * scale[k0 + lk + 1] + shift[k0 + lk + 1], 0.f);
            av.z = fmaxf(av.z * scale[k0 + lk + 2] + shift[k0 + lk + 2], 0.f);
            av.w = fmaxf(av.w * scale[k0 + lk + 3] + shift[k0 + lk + 3], 0.f);
        }
        As[lk + 0][lr] = av.x;
        As[lk + 1][lr] = av.y;
        As[lk + 2][lr] = av.z;
        As[lk + 3][lr] = av.w;
        float4 wv = *reinterpret_cast<const float4*>(&W[(size_t)(j0 + lr) * K + k0 + lk]);
        Ws[lk + 0][lr] = wv.x;
        Ws[lk + 1][lr] = wv.y;
        Ws[lk + 2][lr] = wv.z;
        Ws[lk + 3][lr] = wv.w;
        __syncthreads();
#pragma unroll
        for (int kk = 0; kk < 16; ++kk) {
            float a0 = As[kk][r * 4 + 0], a1 = As[kk][r * 4 + 1];
            float a2 = As[kk][r * 4 + 2], a3 = As[kk][r * 4 + 3];
            float b0 = Ws[kk][cg * 4 + 0], b1 = Ws[kk][cg * 4 + 1];
            float b2 = Ws[kk][cg * 4 + 2], b3 = Ws[kk][cg * 4 + 3];
            acc[0][0] += a0 * b0; acc[0][1] += a0 * b1; acc[0][2] += a0 * b2; acc[0][3] += a0 * b3;
            acc[1][0] += a1 * b0; acc[1][1] += a1 * b1; acc[1][2] += a1 * b2; acc[1][3] += a1 * b3;
            acc[2][0] += a2 * b0; acc[2][1] += a2 * b1; acc[2][2] += a2 * b2; acc[2][3] += a2 * b3;
            acc[3][0] += a3 * b0; acc[3][1] += a3 * b1; acc[3][2] += a3 * b2; acc[3][3] += a3 * b3;
        }
        __syncthreads();
    }
#pragma unroll
    for (int i = 0; i < 4; ++i) {
        int m = m0 + r * 4 + i;
        if (m < M) {
#pragma unroll
            for (int j = 0; j < 4; ++j) {
                int col = j0 + cg * 4 + j;
                C[(size_t)m * Nc + col] = acc[i][j] + bias[col];
            }
        }
    }
}

// ---------------- column stats (sum, sumsq) over M rows ----------------
// blockDim.x == C (128 or 256); row stripes per block; atomic partials
__global__ void colstats_kernel(const float* __restrict__ X, int M, int C,
                                float* __restrict__ sums, float* __restrict__ sqs) {
    int c = threadIdx.x;
    int rows = (M + gridDim.x - 1) / gridDim.x;
    int r0 = blockIdx.x * rows;
    int r1 = min(r0 + rows, M);
    float s = 0.f, q = 0.f;
    for (int r = r0; r < r1; ++r) {
        float v = X[(size_t)r * C + c];
        s += v;
        q += v * v;
    }
    atomicAdd(&sums[c], s);
    atomicAdd(&sqs[c], q);
}

__global__ void bnfin_kernel(const float* __restrict__ sums, const float* __restrict__ sqs,
                             const float* __restrict__ g, const float* __restrict__ b,
                             float* __restrict__ scale, float* __restrict__ shift,
                             int C, float invM) {
    int c = blockIdx.x * blockDim.x + threadIdx.x;
    if (c >= C) return;
    float mu = sums[c] * invM;
    float var = fmaxf(sqs[c] * invM - mu * mu, 0.f);
    float is = rsqrtf(var + 1e-5f);
    float sc = g[c] * is;
    scale[c] = sc;
    shift[c] = b[c] - mu * sc;
}

__global__ void bnrelu_kernel(float* __restrict__ h, const float* __restrict__ scale,
                              const float* __restrict__ shift, int total) {
    int idx = blockIdx.x * blockDim.x + threadIdx.x;
    if (idx >= total) return;
    int c = idx & 127;
    h[idx] = fmaxf(h[idx] * scale[c] + shift[c], 0.f);
}

// ---------------- pooling ----------------
__global__ void pool_kernel(const float* __restrict__ h, const int* __restrict__ batch,
                            float* __restrict__ p, int n) {
    int idx = blockIdx.x * blockDim.x + threadIdx.x;
    if (idx >= n * HD) return;
    int node = idx >> 7;
    int c = idx & 127;
    atomicAdd(&p[batch[node] * HD + c], h[idx]);
}

// ---------------- LSTM (1 step, h0=c0=0) + final linear ----------------
__global__ void lstm_kernel(const float* __restrict__ p, const float* __restrict__ wih,
                            const float* __restrict__ bih, const float* __restrict__ bhh,
                            const float* __restrict__ lin_w, const float* __restrict__ lin_b,
                            float* __restrict__ out) {
    __shared__ float pr[HD];
    __shared__ float gates[4 * LHID];
    __shared__ float hh[LHID];
    int g = blockIdx.x;
    int t = threadIdx.x;
    if (t < HD) pr[t] = p[g * HD + t];
    __syncthreads();
    {
        float acc = bih[t] + bhh[t];
        const float* wr = wih + t * HD;
        for (int k = 0; k < HD; ++k) acc += pr[k] * wr[k];
        gates[t] = acc;
    }
    __syncthreads();
    if (t < LHID) {
        float ig = gates[t];
        float gg = gates[2 * LHID + t];
        float og = gates[3 * LHID + t];
        float c = (1.f / (1.f + expf(-ig))) * tanhf(gg);
        hh[t] = (1.f / (1.f + expf(-og))) * tanhf(c);
    }
    __syncthreads();
    if (t < COUT) {
        float acc = lin_b[t];
        const float* lr = lin_w + t * LHID;
        for (int k = 0; k < LHID; ++k) acc += hh[k] * lr[k];
        out[g * COUT + t] = acc;
    }
}

extern "C" void kernel_launch(void* const* d_in, const int* in_sizes, int n_in,
                              void* d_out, int out_size, void* d_ws, size_t ws_size,
                              hipStream_t stream) {
    const float* x        = (const float*)d_in[0];
    const float* ncc      = (const float*)d_in[1];
    const int*   eidx     = (const int*)d_in[2];
    const int*   eattr    = (const int*)d_in[3];
    const int*   batch    = (const int*)d_in[4];
    const float* fc_w     = (const float*)d_in[5];
    const float* fc_b     = (const float*)d_in[6];
    const float* edge_emb = (const float*)d_in[7];
    const float* conv_w1  = (const float*)d_in[8];
    const float* conv_b1  = (const float*)d_in[9];
    const float* conv_bn_g= (const float*)d_in[10];
    const float* conv_bn_b= (const float*)d_in[11];
    const float* conv_w2  = (const float*)d_in[12];
    const float* conv_b2  = (const float*)d_in[13];
    const float* bn_g     = (const float*)d_in[14];
    const float* bn_b     = (const float*)d_in[15];
    const float* lstm_wih = (const float*)d_in[16];
    const float* lstm_whh = (const float*)d_in[17];  // unused (h0=0) except via bhh
    const float* lstm_bih = (const float*)d_in[18];
    const float* lstm_bhh = (const float*)d_in[19];
    const float* lin_w    = (const float*)d_in[20];
    const float* lin_b    = (const float*)d_in[21];
    (void)lstm_whh;
    float* out = (float*)d_out;

    const int* src = eidx;
    const int* dst = eidx + NEDGES;

    // ---- workspace layout ----
    char* ws = (char*)d_ws;
    size_t o = 0;
    auto alloc = [&](size_t bytes) {
        size_t r = o;
        o += (bytes + 255) & ~(size_t)255;
        return r;
    };
    int*   deg    = (int*)(ws + alloc(NNODES * 4));
    int*   off    = (int*)(ws + alloc((NNODES + 1) * 4));
    int*   cursor = (int*)(ws + alloc(NNODES * 4));
    int*   psrc   = (int*)(ws + alloc(NEDGES * 4));
    int*   pattr  = (int*)(ws + alloc(NEDGES * 4));
    float* h      = (float*)(ws + alloc((size_t)NNODES * HD * 4));
    float* x0     = (float*)(ws + alloc((size_t)NNODES * HD * 4));
    float* xmid   = (float*)(ws + alloc((size_t)NNODES * 2 * HD * 4));
    float* statsA = (float*)(ws + alloc(4 * 256 * 4));  // sums, sqs, scale, shift
    float* statsB = (float*)(ws + alloc(4 * 256 * 4));
    float* p      = (float*)(ws + alloc((size_t)NGRAPH * HD * 4));

    float* sumsA = statsA, *sqsA = statsA + 256, *scaleA = statsA + 512, *shiftA = statsA + 768;
    float* sumsB = statsB, *sqsB = statsB + 256, *scaleB = statsB + 512, *shiftB = statsB + 768;

    // ---- CSR build ----
    hipMemsetAsync(deg, 0, NNODES * 4, stream);
    hist_kernel<<<(NEDGES + 255) / 256, 256, 0, stream>>>(dst, deg, NEDGES);
    scan_kernel<<<1, 1024, 0, stream>>>(deg, off, cursor, NNODES);
    scatter_kernel<<<(NEDGES + 255) / 256, 256, 0, stream>>>(src, dst, eattr, cursor, psrc, pattr, NEDGES);

    // ---- input FC ----
    fc_kernel<<<(NNODES * HD + 255) / 256, 256, 0, stream>>>(x, ncc, fc_w, fc_b, h, NNODES);

    const float invN = 1.f / (float)NNODES;
    for (int l = 0; l < NLAYER; ++l) {
        // 1. softmax aggregation -> x0 = agg + h
        agg_kernel<<<(NNODES + 1) / 2, 256, 0, stream>>>(h, off, psrc, pattr, edge_emb, x0, NNODES);
        // 2. GEMM1: xmid = x0 @ w1.T + b1   [N, 2H]
        {
            dim3 grid((NNODES + 63) / 64, (2 * HD) / 64);
            gemm_kernel<false><<<grid, 256, 0, stream>>>(
                x0, conv_w1 + (size_t)l * 2 * HD * HD, conv_b1 + l * 2 * HD,
                nullptr, nullptr, xmid, NNODES, 2 * HD, HD);
        }
        // 3. BN stats of xmid (2H channels)
        hipMemsetAsync(statsA, 0, 2 * 256 * 4, stream);
        colstats_kernel<<<256, 2 * HD, 0, stream>>>(xmid, NNODES, 2 * HD, sumsA, sqsA);
        bnfin_kernel<<<1, 256, 0, stream>>>(sumsA, sqsA, conv_bn_g + l * 2 * HD,
                                            conv_bn_b + l * 2 * HD, scaleA, shiftA, 2 * HD, invN);
        // 4. GEMM2 with fused BN+ReLU on A: h = relu(BN(xmid)) @ w2.T + b2
        {
            dim3 grid((NNODES + 63) / 64, HD / 64);
            gemm_kernel<true><<<grid, 256, 0, stream>>>(
                xmid, conv_w2 + (size_t)l * HD * 2 * HD, conv_b2 + l * HD,
                scaleA, shiftA, h, NNODES, HD, 2 * HD);
        }
        // 5. outer BN stats (H channels) + 6. BN+ReLU in place
        hipMemsetAsync(statsB, 0, 2 * 256 * 4, stream);
        colstats_kernel<<<256, HD, 0, stream>>>(h, NNODES, HD, sumsB, sqsB);
        bnfin_kernel<<<1, 128, 0, stream>>>(sumsB, sqsB, bn_g + l * HD, bn_b + l * HD,
                                            scaleB, shiftB, HD, invN);
        bnrelu_kernel<<<(NNODES * HD + 255) / 256, 256, 0, stream>>>(h, scaleB, shiftB, NNODES * HD);
    }

    // ---- pool ----
    hipMemsetAsync(p, 0, (size_t)NGRAPH * HD * 4, stream);
    pool_kernel<<<(NNODES * HD + 255) / 256, 256, 0, stream>>>(h, batch, p, NNODES);

    // ---- LSTM + linear ----
    lstm_kernel<<<NGRAPH, 256, 0, stream>>>(p, lstm_wih, lstm_bih, lstm_bhh, lin_w, lin_b, out);
}

// Round 2
// 1564.492 us; speedup vs baseline: 1.4146x; 1.4146x over previous
//
#include <hip/hip_runtime.h>
#include <hip/hip_bf16.h>
#include <math.h>

#define NNODES 50000
#define NEDGES 640000
#define NGRAPH 256
#define CIN 32
#define HD 128
#define NLAYER 5
#define LHID 64
#define COUT 10
#define EPS_GEN 1e-7f

// ---------------- CSR build ----------------
__global__ void hist_kernel(const int* __restrict__ dst, int* __restrict__ deg, int e) {
    int i = blockIdx.x * blockDim.x + threadIdx.x;
    if (i < e) atomicAdd(&deg[dst[i]], 1);
}

__global__ void scan_kernel(const int* __restrict__ deg, int* __restrict__ off,
                            int* __restrict__ cursor, int n) {
    __shared__ int tsum[1024];
    int t = threadIdx.x;
    int chunk = (n + 1023) / 1024;
    int beg = t * chunk;
    int end = min(beg + chunk, n);
    int s = 0;
    for (int i = beg; i < end; ++i) s += deg[i];
    tsum[t] = s;
    __syncthreads();
    for (int d = 1; d < 1024; d <<= 1) {
        int v = (t >= d) ? tsum[t - d] : 0;
        __syncthreads();
        tsum[t] += v;
        __syncthreads();
    }
    int run = (t == 0) ? 0 : tsum[t - 1];
    for (int i = beg; i < end; ++i) {
        off[i] = run; cursor[i] = run;
        run += deg[i];
    }
    if (t == 1023) off[n] = tsum[1023];
}

__global__ void scatter_kernel(const int* __restrict__ src, const int* __restrict__ dst,
                               const int* __restrict__ eattr, int* __restrict__ cursor,
                               int* __restrict__ psrc, int* __restrict__ pattr, int e) {
    int i = blockIdx.x * blockDim.x + threadIdx.x;
    if (i < e) {
        int d = dst[i];
        int slot = atomicAdd(&cursor[d], 1);
        psrc[slot] = src[i];
        pattr[slot] = eattr[i];
    }
}

// ---------------- input FC ----------------
__global__ void fc_kernel(const float* __restrict__ x, const float* __restrict__ ncc,
                          const float* __restrict__ w, const float* __restrict__ b,
                          float* __restrict__ h, int n) {
    int idx = blockIdx.x * blockDim.x + threadIdx.x;
    if (idx >= n * HD) return;
    int node = idx >> 7;
    int c = idx & 127;
    const float* wr = w + c * 40;
    const float* xr = x + node * CIN;
    const float* nr = ncc + node * 8;
    float acc = b[c];
#pragma unroll
    for (int k = 0; k < CIN; ++k) acc += xr[k] * wr[k];
#pragma unroll
    for (int k = 0; k < 8; ++k) acc += nr[k] * wr[CIN + k];
    h[idx] = acc;
}

// ---------------- softmax aggregation (online, branchless, native exp) ----------------
// block = 256 threads = 4 nodes; 1 wave per node; lane handles channels c and c+64.
// BN: apply relu(h*scale[c]+shift[c]) to layer input (folds previous outer BN+ReLU).
template <bool BN>
__global__ void agg_kernel(const float* __restrict__ h, const int* __restrict__ off,
                           const int* __restrict__ psrc, const int* __restrict__ pattr,
                           const float* __restrict__ edge_emb,
                           const float* __restrict__ scale, const float* __restrict__ shift,
                           float* __restrict__ x0, int n) {
    __shared__ float ee[4 * HD];
    int tid = threadIdx.x;
    ee[tid] = edge_emb[tid];
    ee[tid + 256] = edge_emb[tid + 256];
    __syncthreads();

    int node = blockIdx.x * 4 + (tid >> 6);
    int c = tid & 63;
    if (node >= n) return;
    int b = off[node], e = off[node + 1];

    float sc0 = 1.f, sh0 = 0.f, sc1 = 1.f, sh1 = 0.f;
    if (BN) { sc0 = scale[c]; sh0 = shift[c]; sc1 = scale[c + 64]; sh1 = shift[c + 64]; }

    float M0 = -INFINITY, S0 = 0.f, T0 = 0.f;
    float M1 = -INFINITY, S1 = 0.f, T1 = 0.f;
    for (int j = b; j < e; ++j) {
        int s = __builtin_amdgcn_readfirstlane(psrc[j]);
        int a = __builtin_amdgcn_readfirstlane(pattr[j]);
        float v0 = h[s * HD + c];
        float v1 = h[s * HD + 64 + c];
        if (BN) {
            v0 = fmaxf(fmaf(v0, sc0, sh0), 0.f);
            v1 = fmaxf(fmaf(v1, sc1, sh1), 0.f);
        }
        float msg0 = fmaxf(v0 + ee[a * HD + c], 0.f) + EPS_GEN;
        float msg1 = fmaxf(v1 + ee[a * HD + 64 + c], 0.f) + EPS_GEN;
        float nM0 = fmaxf(M0, msg0);
        float nM1 = fmaxf(M1, msg1);
        float r0 = __expf(M0 - nM0), ev0 = __expf(msg0 - nM0);
        float r1 = __expf(M1 - nM1), ev1 = __expf(msg1 - nM1);
        S0 = fmaf(S0, r0, ev0); T0 = fmaf(T0, r0, ev0 * msg0); M0 = nM0;
        S1 = fmaf(S1, r1, ev1); T1 = fmaf(T1, r1, ev1 * msg1); M1 = nM1;
    }
    float res0 = h[node * HD + c];
    float res1 = h[node * HD + 64 + c];
    if (BN) {
        res0 = fmaxf(fmaf(res0, sc0, sh0), 0.f);
        res1 = fmaxf(fmaf(res1, sc1, sh1), 0.f);
    }
    float agg0 = (e > b) ? (T0 / S0) : 0.f;
    float agg1 = (e > b) ? (T1 / S1) : 0.f;
    x0[node * HD + c] = agg0 + res0;
    x0[node * HD + 64 + c] = agg1 + res1;
}

// ---------------- fp32 GEMM 128x128 tile, BK=16, 8x8/thread, fused col-stats ----------------
// C[M,Nc] = op(A)[M,K] @ W[Nc,K]^T + bias ; op = relu(a*scale[k]+shift[k]) if TRANS
// Also atomically accumulates column sums / sumsq of C into sums/sqs (for next BN).
template <bool TRANS>
__global__ __launch_bounds__(256) void gemm_kernel(
    const float* __restrict__ A, const float* __restrict__ W,
    const float* __restrict__ bias,
    const float* __restrict__ scale, const float* __restrict__ shift,
    float* __restrict__ C, float* __restrict__ sums, float* __restrict__ sqs,
    int M, int Nc, int K) {
    __shared__ float As[16][132];
    __shared__ float Bs[16][132];
    __shared__ float scol[128];
    __shared__ float sqcol[128];
    int tid = threadIdx.x;
    if (tid < 128) { scol[tid] = 0.f; sqcol[tid] = 0.f; }
    int m0 = blockIdx.x * 128;
    int n0 = blockIdx.y * 128;
    int ldr = tid >> 1;            // 0..127
    int ldk = (tid & 1) * 8;       // 0 or 8
    int r = tid >> 4;              // 0..15
    int cg = tid & 15;             // 0..15

    float acc[8][8];
#pragma unroll
    for (int i = 0; i < 8; ++i)
#pragma unroll
        for (int j = 0; j < 8; ++j) acc[i][j] = 0.f;

    for (int k0 = 0; k0 < K; k0 += 16) {
        int am = m0 + ldr;
        float4 a0 = make_float4(0.f, 0.f, 0.f, 0.f), a1 = a0;
        if (am < M) {
            const float* ap = &A[(size_t)am * K + k0 + ldk];
            a0 = *reinterpret_cast<const float4*>(ap);
            a1 = *reinterpret_cast<const float4*>(ap + 4);
        }
        if (TRANS) {
            int kg = k0 + ldk;
            a0.x = fmaxf(fmaf(a0.x, scale[kg + 0], shift[kg + 0]), 0.f);
            a0.y = fmaxf(fmaf(a0.y, scale[kg + 1], shift[kg + 1]), 0.f);
            a0.z = fmaxf(fmaf(a0.z, scale[kg + 2], shift[kg + 2]), 0.f);
            a0.w = fmaxf(fmaf(a0.w, scale[kg + 3], shift[kg + 3]), 0.f);
            a1.x = fmaxf(fmaf(a1.x, scale[kg + 4], shift[kg + 4]), 0.f);
            a1.y = fmaxf(fmaf(a1.y, scale[kg + 5], shift[kg + 5]), 0.f);
            a1.z = fmaxf(fmaf(a1.z, scale[kg + 6], shift[kg + 6]), 0.f);
            a1.w = fmaxf(fmaf(a1.w, scale[kg + 7], shift[kg + 7]), 0.f);
        }
        As[ldk + 0][ldr] = a0.x; As[ldk + 1][ldr] = a0.y;
        As[ldk + 2][ldr] = a0.z; As[ldk + 3][ldr] = a0.w;
        As[ldk + 4][ldr] = a1.x; As[ldk + 5][ldr] = a1.y;
        As[ldk + 6][ldr] = a1.z; As[ldk + 7][ldr] = a1.w;
        {
            const float* wp = &W[(size_t)(n0 + ldr) * K + k0 + ldk];
            float4 b0 = *reinterpret_cast<const float4*>(wp);
            float4 b1 = *reinterpret_cast<const float4*>(wp + 4);
            Bs[ldk + 0][ldr] = b0.x; Bs[ldk + 1][ldr] = b0.y;
            Bs[ldk + 2][ldr] = b0.z; Bs[ldk + 3][ldr] = b0.w;
            Bs[ldk + 4][ldr] = b1.x; Bs[ldk + 5][ldr] = b1.y;
            Bs[ldk + 6][ldr] = b1.z; Bs[ldk + 7][ldr] = b1.w;
        }
        __syncthreads();
#pragma unroll
        for (int kk = 0; kk < 16; ++kk) {
            float4 av0 = *reinterpret_cast<const float4*>(&As[kk][r * 8]);
            float4 av1 = *reinterpret_cast<const float4*>(&As[kk][r * 8 + 4]);
            float4 bv0 = *reinterpret_cast<const float4*>(&Bs[kk][cg * 8]);
            float4 bv1 = *reinterpret_cast<const float4*>(&Bs[kk][cg * 8 + 4]);
            float av[8] = {av0.x, av0.y, av0.z, av0.w, av1.x, av1.y, av1.z, av1.w};
            float bv[8] = {bv0.x, bv0.y, bv0.z, bv0.w, bv1.x, bv1.y, bv1.z, bv1.w};
#pragma unroll
            for (int i = 0; i < 8; ++i)
#pragma unroll
                for (int j = 0; j < 8; ++j) acc[i][j] = fmaf(av[i], bv[j], acc[i][j]);
        }
        __syncthreads();
    }

    float bj[8];
#pragma unroll
    for (int j = 0; j < 8; ++j) bj[j] = bias[n0 + cg * 8 + j];

#pragma unroll
    for (int i = 0; i < 8; ++i) {
        int m = m0 + r * 8 + i;
        if (m < M) {
#pragma unroll
            for (int j = 0; j < 8; ++j) acc[i][j] += bj[j];
            float* cp = &C[(size_t)m * Nc + n0 + cg * 8];
            *reinterpret_cast<float4*>(cp) = make_float4(acc[i][0], acc[i][1], acc[i][2], acc[i][3]);
            *reinterpret_cast<float4*>(cp + 4) = make_float4(acc[i][4], acc[i][5], acc[i][6], acc[i][7]);
        }
    }
    // column stats of this tile
#pragma unroll
    for (int j = 0; j < 8; ++j) {
        float cs = 0.f, cq = 0.f;
#pragma unroll
        for (int i = 0; i < 8; ++i) {
            int m = m0 + r * 8 + i;
            if (m < M) { float v = acc[i][j]; cs += v; cq += v * v; }
        }
        atomicAdd(&scol[cg * 8 + j], cs);
        atomicAdd(&sqcol[cg * 8 + j], cq);
    }
    __syncthreads();
    if (tid < 128) {
        atomicAdd(&sums[n0 + tid], scol[tid]);
        atomicAdd(&sqs[n0 + tid], sqcol[tid]);
    }
}

// ---------------- BN finalize ----------------
__global__ void bnfin_kernel(const float* __restrict__ sums, const float* __restrict__ sqs,
                             const float* __restrict__ g, const float* __restrict__ b,
                             float* __restrict__ scale, float* __restrict__ shift,
                             int C, float invM) {
    int c = blockIdx.x * blockDim.x + threadIdx.x;
    if (c >= C) return;
    float mu = sums[c] * invM;
    float var = fmaxf(sqs[c] * invM - mu * mu, 0.f);
    float is = rsqrtf(var + 1e-5f);
    float sc = g[c] * is;
    scale[c] = sc;
    shift[c] = b[c] - mu * sc;
}

// ---------------- pooling (with folded final BN+ReLU) ----------------
__global__ void pool_kernel(const float* __restrict__ h, const int* __restrict__ batch,
                            const float* __restrict__ scale, const float* __restrict__ shift,
                            float* __restrict__ p, int n) {
    int idx = blockIdx.x * blockDim.x + threadIdx.x;
    if (idx >= n * HD) return;
    int node = idx >> 7;
    int c = idx & 127;
    float v = fmaxf(fmaf(h[idx], scale[c], shift[c]), 0.f);
    atomicAdd(&p[batch[node] * HD + c], v);
}

// ---------------- LSTM (1 step) + final linear ----------------
__global__ void lstm_kernel(const float* __restrict__ p, const float* __restrict__ wih,
                            const float* __restrict__ bih, const float* __restrict__ bhh,
                            const float* __restrict__ lin_w, const float* __restrict__ lin_b,
                            float* __restrict__ out) {
    __shared__ float pr[HD];
    __shared__ float gates[4 * LHID];
    __shared__ float hh[LHID];
    int g = blockIdx.x;
    int t = threadIdx.x;
    if (t < HD) pr[t] = p[g * HD + t];
    __syncthreads();
    {
        float acc = bih[t] + bhh[t];
        const float* wr = wih + t * HD;
        for (int k = 0; k < HD; ++k) acc += pr[k] * wr[k];
        gates[t] = acc;
    }
    __syncthreads();
    if (t < LHID) {
        float ig = gates[t];
        float gg = gates[2 * LHID + t];
        float og = gates[3 * LHID + t];
        float c = (1.f / (1.f + __expf(-ig))) * tanhf(gg);
        hh[t] = (1.f / (1.f + __expf(-og))) * tanhf(c);
    }
    __syncthreads();
    if (t < COUT) {
        float acc = lin_b[t];
        const float* lr = lin_w + t * LHID;
        for (int k = 0; k < LHID; ++k) acc += hh[k] * lr[k];
        out[g * COUT + t] = acc;
    }
}

extern "C" void kernel_launch(void* const* d_in, const int* in_sizes, int n_in,
                              void* d_out, int out_size, void* d_ws, size_t ws_size,
                              hipStream_t stream) {
    const float* x        = (const float*)d_in[0];
    const float* ncc      = (const float*)d_in[1];
    const int*   eidx     = (const int*)d_in[2];
    const int*   eattr    = (const int*)d_in[3];
    const int*   batch    = (const int*)d_in[4];
    const float* fc_w     = (const float*)d_in[5];
    const float* fc_b     = (const float*)d_in[6];
    const float* edge_emb = (const float*)d_in[7];
    const float* conv_w1  = (const float*)d_in[8];
    const float* conv_b1  = (const float*)d_in[9];
    const float* conv_bn_g= (const float*)d_in[10];
    const float* conv_bn_b= (const float*)d_in[11];
    const float* conv_w2  = (const float*)d_in[12];
    const float* conv_b2  = (const float*)d_in[13];
    const float* bn_g     = (const float*)d_in[14];
    const float* bn_b     = (const float*)d_in[15];
    const float* lstm_wih = (const float*)d_in[16];
    const float* lstm_bih = (const float*)d_in[18];
    const float* lstm_bhh = (const float*)d_in[19];
    const float* lin_w    = (const float*)d_in[20];
    const float* lin_b    = (const float*)d_in[21];
    float* out = (float*)d_out;

    const int* src = eidx;
    const int* dst = eidx + NEDGES;

    char* ws = (char*)d_ws;
    size_t o = 0;
    auto alloc = [&](size_t bytes) {
        size_t r = o;
        o += (bytes + 255) & ~(size_t)255;
        return r;
    };
    int*   deg    = (int*)(ws + alloc(NNODES * 4));
    int*   off    = (int*)(ws + alloc((NNODES + 1) * 4));
    int*   cursor = (int*)(ws + alloc(NNODES * 4));
    int*   psrc   = (int*)(ws + alloc(NEDGES * 4));
    int*   pattr  = (int*)(ws + alloc(NEDGES * 4));
    float* h      = (float*)(ws + alloc((size_t)NNODES * HD * 4));
    float* x0     = (float*)(ws + alloc((size_t)NNODES * HD * 4));
    float* xmid   = (float*)(ws + alloc((size_t)NNODES * 2 * HD * 4));
    float* statsA = (float*)(ws + alloc(4 * 256 * 4));
    float* statsB = (float*)(ws + alloc(4 * 256 * 4));
    float* p      = (float*)(ws + alloc((size_t)NGRAPH * HD * 4));

    float* sumsA = statsA, *sqsA = statsA + 256, *scaleA = statsA + 512, *shiftA = statsA + 768;
    float* sumsB = statsB, *sqsB = statsB + 256, *scaleB = statsB + 512, *shiftB = statsB + 768;

    // ---- CSR build ----
    hipMemsetAsync(deg, 0, NNODES * 4, stream);
    hist_kernel<<<(NEDGES + 255) / 256, 256, 0, stream>>>(dst, deg, NEDGES);
    scan_kernel<<<1, 1024, 0, stream>>>(deg, off, cursor, NNODES);
    scatter_kernel<<<(NEDGES + 255) / 256, 256, 0, stream>>>(src, dst, eattr, cursor, psrc, pattr, NEDGES);

    // ---- input FC ----
    fc_kernel<<<(NNODES * HD + 255) / 256, 256, 0, stream>>>(x, ncc, fc_w, fc_b, h, NNODES);

    const float invN = 1.f / (float)NNODES;
    const int aggGrid = (NNODES + 3) / 4;
    for (int l = 0; l < NLAYER; ++l) {
        // 1. softmax aggregation (+ folded previous outer BN+ReLU) -> x0
        if (l == 0)
            agg_kernel<false><<<aggGrid, 256, 0, stream>>>(h, off, psrc, pattr, edge_emb,
                                                           nullptr, nullptr, x0, NNODES);
        else
            agg_kernel<true><<<aggGrid, 256, 0, stream>>>(h, off, psrc, pattr, edge_emb,
                                                          scaleB, shiftB, x0, NNODES);
        // 2. GEMM1: xmid = x0 @ w1.T + b1  (+ stats for conv BN)
        hipMemsetAsync(statsA, 0, 512 * 4, stream);
        {
            dim3 grid((NNODES + 127) / 128, 2);
            gemm_kernel<false><<<grid, 256, 0, stream>>>(
                x0, conv_w1 + (size_t)l * 2 * HD * HD, conv_b1 + l * 2 * HD,
                nullptr, nullptr, xmid, sumsA, sqsA, NNODES, 2 * HD, HD);
        }
        bnfin_kernel<<<1, 256, 0, stream>>>(sumsA, sqsA, conv_bn_g + l * 2 * HD,
                                            conv_bn_b + l * 2 * HD, scaleA, shiftA, 2 * HD, invN);
        // 3. GEMM2 (fused BN+ReLU on A): h = relu(BN(xmid)) @ w2.T + b2  (+ stats for outer BN)
        hipMemsetAsync(statsB, 0, 512 * 4, stream);
        {
            dim3 grid((NNODES + 127) / 128, 1);
            gemm_kernel<true><<<grid, 256, 0, stream>>>(
                xmid, conv_w2 + (size_t)l * HD * 2 * HD, conv_b2 + l * HD,
                scaleA, shiftA, h, sumsB, sqsB, NNODES, HD, 2 * HD);
        }
        bnfin_kernel<<<1, 128, 0, stream>>>(sumsB, sqsB, bn_g + l * HD, bn_b + l * HD,
                                            scaleB, shiftB, HD, invN);
    }

    // ---- pool (final BN+ReLU folded) ----
    hipMemsetAsync(p, 0, (size_t)NGRAPH * HD * 4, stream);
    pool_kernel<<<(NNODES * HD + 255) / 256, 256, 0, stream>>>(h, batch, scaleB, shiftB, p, NNODES);

    // ---- LSTM + linear ----
    lstm_kernel<<<NGRAPH, 256, 0, stream>>>(p, lstm_wih, lstm_bih, lstm_bhh, lin_w, lin_b, out);
}

// Round 3
// 1280.478 us; speedup vs baseline: 1.7284x; 1.2218x over previous
//
#include <hip/hip_runtime.h>
#include <hip/hip_bf16.h>
#include <math.h>

#define NNODES 50000
#define NEDGES 640000
#define NGRAPH 256
#define CIN 32
#define HD 128
#define NLAYER 5
#define LHID 64
#define COUT 10
#define EPS_GEN 1e-7f
#define INVN (1.f / (float)NNODES)
#define SCAN_BLOCKS 196

// ---------------- CSR build ----------------
__global__ void hist_kernel(const int* __restrict__ dst, int* __restrict__ deg, int e) {
    int i = blockIdx.x * blockDim.x + threadIdx.x;
    if (i < e) atomicAdd(&deg[dst[i]], 1);
}

__global__ void blocksum_kernel(const int* __restrict__ deg, int* __restrict__ bsum) {
    int i = blockIdx.x * 256 + threadIdx.x;
    int v = (i < NNODES) ? deg[i] : 0;
#pragma unroll
    for (int d = 32; d; d >>= 1) v += __shfl_down(v, d);
    __shared__ int ws4[4];
    if ((threadIdx.x & 63) == 0) ws4[threadIdx.x >> 6] = v;
    __syncthreads();
    if (threadIdx.x == 0) bsum[blockIdx.x] = ws4[0] + ws4[1] + ws4[2] + ws4[3];
}

__global__ void scanpartials_kernel(const int* __restrict__ bsum, int* __restrict__ bpre) {
    __shared__ int t[256];
    int i = threadIdx.x;
    t[i] = (i < SCAN_BLOCKS) ? bsum[i] : 0;
    __syncthreads();
    for (int d = 1; d < 256; d <<= 1) {
        int v = (i >= d) ? t[i - d] : 0;
        __syncthreads();
        t[i] += v;
        __syncthreads();
    }
    bpre[i] = (i == 0) ? 0 : t[i - 1];
}

__global__ void writeoff_kernel(const int* __restrict__ deg, const int* __restrict__ bpre,
                                int* __restrict__ off, int* __restrict__ cursor) {
    __shared__ int t[256];
    int tid = threadIdx.x;
    int i = blockIdx.x * 256 + tid;
    int v = (i < NNODES) ? deg[i] : 0;
    t[tid] = v;
    __syncthreads();
    for (int d = 1; d < 256; d <<= 1) {
        int u = (tid >= d) ? t[tid - d] : 0;
        __syncthreads();
        t[tid] += u;
        __syncthreads();
    }
    int excl = bpre[blockIdx.x] + t[tid] - v;
    if (i < NNODES) { off[i] = excl; cursor[i] = excl; }
    if (i == NNODES - 1) off[NNODES] = excl + v;
}

__global__ void scatter_kernel(const int* __restrict__ src, const int* __restrict__ dst,
                               const int* __restrict__ eattr, int* __restrict__ cursor,
                               int* __restrict__ pedge, int e) {
    int i = blockIdx.x * blockDim.x + threadIdx.x;
    if (i < e) {
        int slot = atomicAdd(&cursor[dst[i]], 1);
        pedge[slot] = src[i] | (eattr[i] << 27);
    }
}

// ---------------- input FC ----------------
__global__ void fc_kernel(const float* __restrict__ x, const float* __restrict__ ncc,
                          const float* __restrict__ w, const float* __restrict__ b,
                          float* __restrict__ h, int n) {
    int idx = blockIdx.x * blockDim.x + threadIdx.x;
    if (idx >= n * HD) return;
    int node = idx >> 7;
    int c = idx & 127;
    const float* wr = w + c * 40;
    const float* xr = x + node * CIN;
    const float* nr = ncc + node * 8;
    float acc = b[c];
#pragma unroll
    for (int k = 0; k < CIN; ++k) acc += xr[k] * wr[k];
#pragma unroll
    for (int k = 0; k < 8; ++k) acc += nr[k] * wr[CIN + k];
    h[idx] = acc;
}

// ---------------- softmax aggregation ----------------
// 256 thr = 4 waves = 4 nodes. Within a wave: half (32 lanes) per edge, lane
// holds 4 channels (float4). No max-tracking (args bounded, exp safe in fp32).
// BN: folds previous outer BN+ReLU (computed in-block from raw sums).
template <bool BN>
__global__ __launch_bounds__(256) void agg_kernel(
    const float* __restrict__ h, const int* __restrict__ off,
    const int* __restrict__ pedge, const float* __restrict__ edge_emb,
    const float* __restrict__ sums, const float* __restrict__ sqs,
    const float* __restrict__ g, const float* __restrict__ bb,
    float* __restrict__ x0) {
    __shared__ float ee[4 * HD];
    __shared__ float scs[HD], shs[HD];
    int tid = threadIdx.x;
    ee[tid] = edge_emb[tid];
    ee[tid + 256] = edge_emb[tid + 256];
    if (BN && tid < HD) {
        float mu = sums[tid] * INVN;
        float var = fmaxf(sqs[tid] * INVN - mu * mu, 0.f);
        float is = rsqrtf(var + 1e-5f);
        float sc = g[tid] * is;
        scs[tid] = sc;
        shs[tid] = bb[tid] - mu * sc;
    }
    __syncthreads();

    int node = blockIdx.x * 4 + (tid >> 6);
    int lane = tid & 63;
    int half = lane >> 5;
    int c4 = (lane & 31) * 4;

    int b = off[node], e = off[node + 1];
    float4 sc4 = make_float4(1.f, 1.f, 1.f, 1.f);
    float4 sh4 = make_float4(0.f, 0.f, 0.f, 0.f);
    if (BN) {
        sc4 = *reinterpret_cast<const float4*>(&scs[c4]);
        sh4 = *reinterpret_cast<const float4*>(&shs[c4]);
    }
    float4 S = make_float4(0.f, 0.f, 0.f, 0.f);
    float4 T = make_float4(0.f, 0.f, 0.f, 0.f);
    for (int j = b + half; j < e; j += 2) {
        unsigned p = (unsigned)pedge[j];
        int s = p & 0x07FFFFFFu;
        int a = p >> 27;
        float4 v = *reinterpret_cast<const float4*>(&h[(size_t)s * HD + c4]);
        float4 ev = *reinterpret_cast<const float4*>(&ee[a * HD + c4]);
        if (BN) {
            v.x = fmaxf(fmaf(v.x, sc4.x, sh4.x), 0.f);
            v.y = fmaxf(fmaf(v.y, sc4.y, sh4.y), 0.f);
            v.z = fmaxf(fmaf(v.z, sc4.z, sh4.z), 0.f);
            v.w = fmaxf(fmaf(v.w, sc4.w, sh4.w), 0.f);
        }
        float m0 = fmaxf(v.x + ev.x, 0.f) + EPS_GEN;
        float m1 = fmaxf(v.y + ev.y, 0.f) + EPS_GEN;
        float m2 = fmaxf(v.z + ev.z, 0.f) + EPS_GEN;
        float m3 = fmaxf(v.w + ev.w, 0.f) + EPS_GEN;
        float e0 = __expf(m0), e1 = __expf(m1), e2 = __expf(m2), e3 = __expf(m3);
        S.x += e0; S.y += e1; S.z += e2; S.w += e3;
        T.x = fmaf(e0, m0, T.x); T.y = fmaf(e1, m1, T.y);
        T.z = fmaf(e2, m2, T.z); T.w = fmaf(e3, m3, T.w);
    }
    // merge the two half-wave softmax states
    S.x += __shfl(S.x, lane ^ 32); S.y += __shfl(S.y, lane ^ 32);
    S.z += __shfl(S.z, lane ^ 32); S.w += __shfl(S.w, lane ^ 32);
    T.x += __shfl(T.x, lane ^ 32); T.y += __shfl(T.y, lane ^ 32);
    T.z += __shfl(T.z, lane ^ 32); T.w += __shfl(T.w, lane ^ 32);
    if (half == 0) {
        float4 r = *reinterpret_cast<const float4*>(&h[(size_t)node * HD + c4]);
        if (BN) {
            r.x = fmaxf(fmaf(r.x, sc4.x, sh4.x), 0.f);
            r.y = fmaxf(fmaf(r.y, sc4.y, sh4.y), 0.f);
            r.z = fmaxf(fmaf(r.z, sc4.z, sh4.z), 0.f);
            r.w = fmaxf(fmaf(r.w, sc4.w, sh4.w), 0.f);
        }
        if (e > b) {
            r.x += T.x / S.x; r.y += T.y / S.y;
            r.z += T.z / S.z; r.w += T.w / S.w;
        }
        *reinterpret_cast<float4*>(&x0[(size_t)node * HD + c4]) = r;
    }
}

// ---------------- fp32 GEMM 128x128 tile, BK=16, 8x8/thread ----------------
// C = op(A) @ W^T + bias; op = relu(a*scale+shift) with scale/shift computed
// in-block from raw sums (TRANS). Fused column sum/sumsq stats of C.
template <bool TRANS>
__global__ __launch_bounds__(256) void gemm_kernel(
    const float* __restrict__ A, const float* __restrict__ W,
    const float* __restrict__ bias,
    const float* __restrict__ sums_in, const float* __restrict__ sqs_in,
    const float* __restrict__ g_in, const float* __restrict__ b_in,
    float* __restrict__ C, float* __restrict__ sums, float* __restrict__ sqs,
    int M, int Nc, int K) {
    __shared__ float As[16][132];
    __shared__ float Bs[16][132];
    __shared__ float scol[128];
    __shared__ float sqcol[128];
    __shared__ float sL[256], shL[256];
    int tid = threadIdx.x;
    if (tid < 128) { scol[tid] = 0.f; sqcol[tid] = 0.f; }
    if (TRANS && tid < K) {
        float mu = sums_in[tid] * INVN;
        float var = fmaxf(sqs_in[tid] * INVN - mu * mu, 0.f);
        float is = rsqrtf(var + 1e-5f);
        float sc = g_in[tid] * is;
        sL[tid] = sc;
        shL[tid] = b_in[tid] - mu * sc;
    }
    __syncthreads();

    int m0 = blockIdx.x * 128;
    int n0 = blockIdx.y * 128;
    int ldr = tid >> 1;
    int ldk = (tid & 1) * 8;
    int r = tid >> 4;
    int cg = tid & 15;

    float acc[8][8];
#pragma unroll
    for (int i = 0; i < 8; ++i)
#pragma unroll
        for (int j = 0; j < 8; ++j) acc[i][j] = 0.f;

    for (int k0 = 0; k0 < K; k0 += 16) {
        int am = m0 + ldr;
        float4 a0 = make_float4(0.f, 0.f, 0.f, 0.f), a1 = a0;
        if (am < M) {
            const float* ap = &A[(size_t)am * K + k0 + ldk];
            a0 = *reinterpret_cast<const float4*>(ap);
            a1 = *reinterpret_cast<const float4*>(ap + 4);
        }
        if (TRANS) {
            int kg = k0 + ldk;
            float4 s0 = *reinterpret_cast<const float4*>(&sL[kg]);
            float4 s1 = *reinterpret_cast<const float4*>(&sL[kg + 4]);
            float4 h0 = *reinterpret_cast<const float4*>(&shL[kg]);
            float4 h1 = *reinterpret_cast<const float4*>(&shL[kg + 4]);
            a0.x = fmaxf(fmaf(a0.x, s0.x, h0.x), 0.f);
            a0.y = fmaxf(fmaf(a0.y, s0.y, h0.y), 0.f);
            a0.z = fmaxf(fmaf(a0.z, s0.z, h0.z), 0.f);
            a0.w = fmaxf(fmaf(a0.w, s0.w, h0.w), 0.f);
            a1.x = fmaxf(fmaf(a1.x, s1.x, h1.x), 0.f);
            a1.y = fmaxf(fmaf(a1.y, s1.y, h1.y), 0.f);
            a1.z = fmaxf(fmaf(a1.z, s1.z, h1.z), 0.f);
            a1.w = fmaxf(fmaf(a1.w, s1.w, h1.w), 0.f);
        }
        As[ldk + 0][ldr] = a0.x; As[ldk + 1][ldr] = a0.y;
        As[ldk + 2][ldr] = a0.z; As[ldk + 3][ldr] = a0.w;
        As[ldk + 4][ldr] = a1.x; As[ldk + 5][ldr] = a1.y;
        As[ldk + 6][ldr] = a1.z; As[ldk + 7][ldr] = a1.w;
        {
            const float* wp = &W[(size_t)(n0 + ldr) * K + k0 + ldk];
            float4 b0 = *reinterpret_cast<const float4*>(wp);
            float4 b1 = *reinterpret_cast<const float4*>(wp + 4);
            Bs[ldk + 0][ldr] = b0.x; Bs[ldk + 1][ldr] = b0.y;
            Bs[ldk + 2][ldr] = b0.z; Bs[ldk + 3][ldr] = b0.w;
            Bs[ldk + 4][ldr] = b1.x; Bs[ldk + 5][ldr] = b1.y;
            Bs[ldk + 6][ldr] = b1.z; Bs[ldk + 7][ldr] = b1.w;
        }
        __syncthreads();
#pragma unroll
        for (int kk = 0; kk < 16; ++kk) {
            float4 av0 = *reinterpret_cast<const float4*>(&As[kk][r * 8]);
            float4 av1 = *reinterpret_cast<const float4*>(&As[kk][r * 8 + 4]);
            float4 bv0 = *reinterpret_cast<const float4*>(&Bs[kk][cg * 8]);
            float4 bv1 = *reinterpret_cast<const float4*>(&Bs[kk][cg * 8 + 4]);
            float av[8] = {av0.x, av0.y, av0.z, av0.w, av1.x, av1.y, av1.z, av1.w};
            float bv[8] = {bv0.x, bv0.y, bv0.z, bv0.w, bv1.x, bv1.y, bv1.z, bv1.w};
#pragma unroll
            for (int i = 0; i < 8; ++i)
#pragma unroll
                for (int j = 0; j < 8; ++j) acc[i][j] = fmaf(av[i], bv[j], acc[i][j]);
        }
        __syncthreads();
    }

    float bj[8];
#pragma unroll
    for (int j = 0; j < 8; ++j) bj[j] = bias[n0 + cg * 8 + j];

#pragma unroll
    for (int i = 0; i < 8; ++i) {
        int m = m0 + r * 8 + i;
        if (m < M) {
#pragma unroll
            for (int j = 0; j < 8; ++j) acc[i][j] += bj[j];
            float* cp = &C[(size_t)m * Nc + n0 + cg * 8];
            *reinterpret_cast<float4*>(cp) = make_float4(acc[i][0], acc[i][1], acc[i][2], acc[i][3]);
            *reinterpret_cast<float4*>(cp + 4) = make_float4(acc[i][4], acc[i][5], acc[i][6], acc[i][7]);
        }
    }
#pragma unroll
    for (int j = 0; j < 8; ++j) {
        float cs = 0.f, cq = 0.f;
#pragma unroll
        for (int i = 0; i < 8; ++i) {
            int m = m0 + r * 8 + i;
            if (m < M) { float v = acc[i][j]; cs += v; cq += v * v; }
        }
        atomicAdd(&scol[cg * 8 + j], cs);
        atomicAdd(&sqcol[cg * 8 + j], cq);
    }
    __syncthreads();
    if (tid < 128) {
        atomicAdd(&sums[n0 + tid], scol[tid]);
        atomicAdd(&sqs[n0 + tid], sqcol[tid]);
    }
}

// ---------------- segmented pool (batch sorted) + folded final BN+ReLU ----------------
__global__ void pool_kernel(const float* __restrict__ h, const int* __restrict__ batch,
                            const float* __restrict__ sums, const float* __restrict__ sqs,
                            const float* __restrict__ g, const float* __restrict__ bb,
                            float* __restrict__ p) {
    __shared__ int range[2];
    __shared__ float acc2[256];
    int gid = blockIdx.x;
    int tid = threadIdx.x;
    if (tid < 2) {
        int target = gid + tid;
        int lo = 0, hi = NNODES;
        while (lo < hi) {
            int mid = (lo + hi) >> 1;
            if (batch[mid] < target) lo = mid + 1; else hi = mid;
        }
        range[tid] = lo;
    }
    __syncthreads();
    int s0 = range[0], s1 = range[1];
    int c = tid & 127;
    int half = tid >> 7;
    float mu = sums[c] * INVN;
    float var = fmaxf(sqs[c] * INVN - mu * mu, 0.f);
    float is = rsqrtf(var + 1e-5f);
    float sc = g[c] * is;
    float sh = bb[c] - mu * sc;
    float a = 0.f;
    for (int r = s0 + half; r < s1; r += 2)
        a += fmaxf(fmaf(h[(size_t)r * HD + c], sc, sh), 0.f);
    acc2[tid] = a;
    __syncthreads();
    if (half == 0) p[gid * HD + c] = acc2[c] + acc2[c + 128];
}

// ---------------- LSTM (1 step) + final linear ----------------
__global__ void lstm_kernel(const float* __restrict__ p, const float* __restrict__ wih,
                            const float* __restrict__ bih, const float* __restrict__ bhh,
                            const float* __restrict__ lin_w, const float* __restrict__ lin_b,
                            float* __restrict__ out) {
    __shared__ float pr[HD];
    __shared__ float gates[4 * LHID];
    __shared__ float hh[LHID];
    int g = blockIdx.x;
    int t = threadIdx.x;
    if (t < HD) pr[t] = p[g * HD + t];
    __syncthreads();
    {
        float acc = bih[t] + bhh[t];
        const float* wr = wih + t * HD;
        for (int k = 0; k < HD; ++k) acc += pr[k] * wr[k];
        gates[t] = acc;
    }
    __syncthreads();
    if (t < LHID) {
        float ig = gates[t];
        float gg = gates[2 * LHID + t];
        float og = gates[3 * LHID + t];
        float c = (1.f / (1.f + __expf(-ig))) * tanhf(gg);
        hh[t] = (1.f / (1.f + __expf(-og))) * tanhf(c);
    }
    __syncthreads();
    if (t < COUT) {
        float acc = lin_b[t];
        const float* lr = lin_w + t * LHID;
        for (int k = 0; k < LHID; ++k) acc += hh[k] * lr[k];
        out[g * COUT + t] = acc;
    }
}

extern "C" void kernel_launch(void* const* d_in, const int* in_sizes, int n_in,
                              void* d_out, int out_size, void* d_ws, size_t ws_size,
                              hipStream_t stream) {
    const float* x        = (const float*)d_in[0];
    const float* ncc      = (const float*)d_in[1];
    const int*   eidx     = (const int*)d_in[2];
    const int*   eattr    = (const int*)d_in[3];
    const int*   batch    = (const int*)d_in[4];
    const float* fc_w     = (const float*)d_in[5];
    const float* fc_b     = (const float*)d_in[6];
    const float* edge_emb = (const float*)d_in[7];
    const float* conv_w1  = (const float*)d_in[8];
    const float* conv_b1  = (const float*)d_in[9];
    const float* conv_bn_g= (const float*)d_in[10];
    const float* conv_bn_b= (const float*)d_in[11];
    const float* conv_w2  = (const float*)d_in[12];
    const float* conv_b2  = (const float*)d_in[13];
    const float* bn_g     = (const float*)d_in[14];
    const float* bn_b     = (const float*)d_in[15];
    const float* lstm_wih = (const float*)d_in[16];
    const float* lstm_bih = (const float*)d_in[18];
    const float* lstm_bhh = (const float*)d_in[19];
    const float* lin_w    = (const float*)d_in[20];
    const float* lin_b    = (const float*)d_in[21];
    float* out = (float*)d_out;

    const int* src = eidx;
    const int* dst = eidx + NEDGES;

    char* ws = (char*)d_ws;
    size_t o = 0;
    auto alloc = [&](size_t bytes) {
        size_t r = o;
        o += (bytes + 255) & ~(size_t)255;
        return r;
    };
    int*   deg    = (int*)(ws + alloc(NNODES * 4));
    int*   off    = (int*)(ws + alloc((NNODES + 1) * 4));
    int*   cursor = (int*)(ws + alloc(NNODES * 4));
    int*   pedge  = (int*)(ws + alloc(NEDGES * 4));
    int*   bsum   = (int*)(ws + alloc(256 * 4));
    int*   bpre   = (int*)(ws + alloc(256 * 4));
    float* h      = (float*)(ws + alloc((size_t)NNODES * HD * 4));
    float* x0     = (float*)(ws + alloc((size_t)NNODES * HD * 4));
    float* xmid   = (float*)(ws + alloc((size_t)NNODES * 2 * HD * 4));
    float* stats  = (float*)(ws + alloc(NLAYER * 768 * 4));  // per layer: sumsA(256),sqsA(256),sumsB(128),sqsB(128)
    float* p      = (float*)(ws + alloc((size_t)NGRAPH * HD * 4));

    // ---- CSR build ----
    hipMemsetAsync(deg, 0, NNODES * 4, stream);
    hipMemsetAsync(stats, 0, NLAYER * 768 * 4, stream);
    hist_kernel<<<(NEDGES + 255) / 256, 256, 0, stream>>>(dst, deg, NEDGES);
    blocksum_kernel<<<SCAN_BLOCKS, 256, 0, stream>>>(deg, bsum);
    scanpartials_kernel<<<1, 256, 0, stream>>>(bsum, bpre);
    writeoff_kernel<<<SCAN_BLOCKS, 256, 0, stream>>>(deg, bpre, off, cursor);
    scatter_kernel<<<(NEDGES + 255) / 256, 256, 0, stream>>>(src, dst, eattr, cursor, pedge, NEDGES);

    // ---- input FC ----
    fc_kernel<<<(NNODES * HD + 255) / 256, 256, 0, stream>>>(x, ncc, fc_w, fc_b, h, NNODES);

    for (int l = 0; l < NLAYER; ++l) {
        float* sumsA = stats + l * 768;
        float* sqsA  = sumsA + 256;
        float* sumsB = sumsA + 512;
        float* sqsB  = sumsA + 640;
        // 1. softmax aggregation (+ folded previous outer BN+ReLU) -> x0
        if (l == 0)
            agg_kernel<false><<<NNODES / 4, 256, 0, stream>>>(
                h, off, pedge, edge_emb, nullptr, nullptr, nullptr, nullptr, x0);
        else {
            float* pB = stats + (l - 1) * 768;
            agg_kernel<true><<<NNODES / 4, 256, 0, stream>>>(
                h, off, pedge, edge_emb, pB + 512, pB + 640,
                bn_g + (l - 1) * HD, bn_b + (l - 1) * HD, x0);
        }
        // 2. GEMM1: xmid = x0 @ w1.T + b1  (+ stats)
        {
            dim3 grid((NNODES + 127) / 128, 2);
            gemm_kernel<false><<<grid, 256, 0, stream>>>(
                x0, conv_w1 + (size_t)l * 2 * HD * HD, conv_b1 + l * 2 * HD,
                nullptr, nullptr, nullptr, nullptr,
                xmid, sumsA, sqsA, NNODES, 2 * HD, HD);
        }
        // 3. GEMM2 (in-block BN fold + ReLU on A): h = relu(BN(xmid)) @ w2.T + b2 (+ stats)
        {
            dim3 grid((NNODES + 127) / 128, 1);
            gemm_kernel<true><<<grid, 256, 0, stream>>>(
                xmid, conv_w2 + (size_t)l * HD * 2 * HD, conv_b2 + l * HD,
                sumsA, sqsA, conv_bn_g + l * 2 * HD, conv_bn_b + l * 2 * HD,
                h, sumsB, sqsB, NNODES, HD, 2 * HD);
        }
    }

    // ---- pool (final outer BN+ReLU folded, segmented, no atomics) ----
    {
        float* pB = stats + (NLAYER - 1) * 768;
        pool_kernel<<<NGRAPH, 256, 0, stream>>>(h, batch, pB + 512, pB + 640,
                                                bn_g + (NLAYER - 1) * HD,
                                                bn_b + (NLAYER - 1) * HD, p);
    }

    // ---- LSTM + linear ----
    lstm_kernel<<<NGRAPH, 256, 0, stream>>>(p, lstm_wih, lstm_bih, lstm_bhh, lin_w, lin_b, out);
}